// Round 4
// baseline (226.163 us; speedup 1.0000x reference)
//
#include <hip/hip_runtime.h>
#include <math.h>

#define NN 32768
#define BB 16
#define LL 2048
#define NE (NN*9)
#define EPSF 1e-6f
#define CAP 48
#define ROWS 16    // rows per topk block
#define CPL 128    // candidates per lane (16 lanes/row)

// ---- output layout (flat float32, reference tuple order) ----
#define O_NODEPOS 0
#define O_DISNODE (NN*16)
#define O_ANGNODE (O_DISNODE + NN*48)
#define O_DIRNODE (O_ANGNODE + NN*12)
#define O_EIDX    (O_DIRNODE + NN*9)
#define O_CTX     (O_EIDX + 2*NE)
#define O_INTER   (O_CTX + NE)
#define O_EDGEPOS (O_INTER + NE)
#define O_DISEDGE (O_EDGEPOS + NE*16)
#define O_ANGEDGE (O_DISEDGE + NE*64)
#define O_DIREDGE (O_ANGEDGE + NE*4)

struct F3 { float x, y, z; };
__device__ __forceinline__ F3 mkf3(float x, float y, float z){ F3 r; r.x=x; r.y=y; r.z=z; return r; }
__device__ __forceinline__ F3 subf3(F3 a, F3 b){ return mkf3(a.x-b.x, a.y-b.y, a.z-b.z); }
__device__ __forceinline__ float dotf3(F3 a, F3 b){ return a.x*b.x + a.y*b.y + a.z*b.z; }
__device__ __forceinline__ F3 crossf3(F3 a, F3 b){
  return mkf3(a.y*b.z - a.z*b.y, a.z*b.x - a.x*b.z, a.x*b.y - a.y*b.x);
}
__device__ __forceinline__ F3 normf3(F3 v){
  float n = sqrtf(v.x*v.x + v.y*v.y + v.z*v.z);
  float m = fmaxf(n, 1e-12f);
  return mkf3(v.x/m, v.y/m, v.z/m);
}
__device__ __forceinline__ float sgnf(float x){ return (x > 0.f) ? 1.f : ((x < 0.f) ? -1.f : 0.f); }
__device__ __forceinline__ float clampf(float x, float lo, float hi){ return fminf(fmaxf(x, lo), hi); }

__device__ __forceinline__ F3 ldatom(const float* __restrict__ X, int n, int a){
  const float* p = X + (size_t)n*12 + a*3;
  return mkf3(p[0], p[1], p[2]);
}
__device__ __forceinline__ float dist_eps(F3 a, F3 b){
  F3 d = subf3(a, b);
  return sqrtf(dotf3(d, d) + EPSF);
}
// freq[t] = 10000^(-t/8), t=0..7
__device__ __forceinline__ float frq(int t){
  const float F[8] = {1.0f, 0.31622776601683794f, 0.1f, 0.031622776601683794f,
                      0.01f, 0.0031622776601683794f, 0.001f, 0.00031622776601683794f};
  return F[t];
}
__device__ __forceinline__ void rbf16(float* __restrict__ dst, float d){
  #pragma unroll
  for (int t = 0; t < 16; ++t){
    float mu = (float)t * (20.0f/15.0f);
    float z = (d - mu) * (1.0f/1.25f);
    dst[t] = __expf(-z*z);
  }
}
// O frame for node n (zero if padded/masked). Rows O0,O1,O2 = o1, nf, o1 x nf.
__device__ __forceinline__ void computeO(const float* __restrict__ X, int n, F3& O0, F3& O1, F3& O2){
  int l = n & (LL-1);
  int b = n >> 11;
  bool fm = !((l <= 1) || ((l >= LL-2) && (b < BB-1)));
  bool has = fm && (n >= 1) && (n <= NN-3);
  if (has){
    F3 cm = ldatom(X, n-1, 1), c0 = ldatom(X, n, 1), cp = ldatom(X, n+1, 1);
    F3 uc2 = normf3(subf3(c0, cm));
    F3 uc1 = normf3(subf3(cp, c0));
    F3 nf  = normf3(crossf3(uc2, uc1));
    F3 o1  = normf3(subf3(uc2, uc1));
    O0 = o1; O1 = nf; O2 = crossf3(o1, nf);
  } else {
    O0 = mkf3(0,0,0); O1 = mkf3(0,0,0); O2 = mkf3(0,0,0);
  }
}

// ================= kernel 1: per-batch top-9 nearest neighbors =================
// 16 lanes/row, 128 candidates/lane. Pass 1 keeps per-lane top-2 VALUES
// (3 min/max per candidate). The 9th-smallest of the merged 16x2 union is a
// subset-statistic, hence >= true s9: a valid rescan threshold. Pass 2 rescans
// with the bit-identical expression and does exact (s,idx)-lex top-9.
__global__ __launch_bounds__(256, 4) void topk_kernel(const float* __restrict__ X,
                                                      float* __restrict__ out){
  __shared__ float4 sca[LL + (LL >> 8)];           // skewed stage of batch CA coords
  __shared__ unsigned long long ebuf[ROWS][CAP];
  __shared__ int ecnt[ROWS];
  const int tid = threadIdx.x;
  const int block0 = blockIdx.x * ROWS;
  const int base = (block0 >> 11) << 11;

  if (tid < ROWS) ecnt[tid] = 0;
  for (int p = tid; p < LL; p += 256){
    const float* xp = X + (size_t)(base + p)*12 + 3;   // CA atom
    sca[p + (p >> 8)] = make_float4(xp[0], xp[1], xp[2], 0.f);
  }
  __syncthreads();

  const int r = tid >> 4;          // row within block (0..15)
  const int k = tid & 15;          // lane group within row
  const int n = block0 + r;
  const int il = n - base;
  const float4 ci = sca[il + (il >> 8)];
  const float4* __restrict__ basep = &sca[k*CPL + (k >> 1)];  // lane's 128 contiguous float4s

  float v0 = __builtin_inff(), v1 = __builtin_inff();

  #pragma unroll 8
  for (int jj = 0; jj < CPL; ++jj){
    const float4 cj = basep[jj];
    const float dx = ci.x - cj.x, dy = ci.y - cj.y, dz = ci.z - cj.z;
    const float key = fmaf(dz, dz, fmaf(dy, dy, dx*dx));
    const float mn = fminf(key, v0);
    const float mx = fmaxf(key, v0);
    v0 = mn;
    v1 = fminf(mx, v1);
  }

  // 9 pop-rounds over the 16 sorted 2-lists -> t9 >= true 9th smallest
  float t9 = 0.f;
  #pragma unroll
  for (int t = 0; t < 9; ++t){
    const float h = v0;
    float m = h;
    m = fminf(m, __shfl_xor(m, 1, 16));
    m = fminf(m, __shfl_xor(m, 2, 16));
    m = fminf(m, __shfl_xor(m, 4, 16));
    m = fminf(m, __shfl_xor(m, 8, 16));
    const bool pop = (h == m);
    v0 = pop ? v1 : v0;
    v1 = pop ? __builtin_inff() : v1;
    t9 = m;
  }

  // rescan: exact (s,idx) for everything at or below the threshold
  const int j0 = k * CPL;
  #pragma unroll 4
  for (int jj = 0; jj < CPL; ++jj){
    const float4 cj = basep[jj];
    const float dx = ci.x - cj.x, dy = ci.y - cj.y, dz = ci.z - cj.z;
    const float s = fmaf(dz, dz, fmaf(dy, dy, dx*dx));   // bit-identical to pass 1
    if (s <= t9){
      const int slot = atomicAdd(&ecnt[r], 1);
      if (slot < CAP)
        ebuf[r][slot] = ((unsigned long long)__float_as_uint(s) << 32) | (unsigned)(j0 + jj);
    }
  }
  __syncthreads();

  if (k == 0){
    const int m = min(ecnt[r], CAP);
    unsigned long long kk[9];
    #pragma unroll
    for (int t = 0; t < 9; ++t) kk[t] = ~0ull;
    for (int j = 0; j < m; ++j){
      unsigned long long key = ebuf[r][j];
      #pragma unroll
      for (int t = 0; t < 9; ++t){
        const bool lt = key < kk[t];
        const unsigned long long mn = lt ? key : kk[t];
        const unsigned long long mx = lt ? kk[t] : key;
        kk[t] = mn; key = mx;
      }
    }
    const int be = n * 9;
    #pragma unroll
    for (int t = 0; t < 9; ++t){
      out[O_EIDX + be + t] = (float)n;
      out[O_EIDX + NE + be + t] = (float)(base + (int)(unsigned)kk[t]);
    }
  }
}

// ================= kernel 2: node features + O-frames to ws =================
__global__ __launch_bounds__(256) void node_kernel(const float* __restrict__ X,
                                                   float* __restrict__ ws,
                                                   float* __restrict__ out){
  const int n = blockIdx.x * 256 + threadIdx.x;
  if (n >= NN) return;
  const int l = n & (LL-1);
  const int b = n >> 11;

  // ---- O frame (also used by direct_node below) ----
  F3 O0, O1, O2;
  computeO(X, n, O0, O1, O2);
  {
    float4* W = (float4*)ws;
    W[n*3 + 0] = make_float4(O0.x, O0.y, O0.z, 0.f);
    W[n*3 + 1] = make_float4(O1.x, O1.y, O1.z, 0.f);
    W[n*3 + 2] = make_float4(O2.x, O2.y, O2.z, 0.f);
  }

  // ---- node_pos ----
  {
    const float p = (float)l;
    #pragma unroll
    for (int t = 0; t < 8; ++t){
      float sv, cv;
      __sincosf(p * frq(t), &sv, &cv);
      out[O_NODEPOS + n*16 + t] = cv;
      out[O_NODEPOS + n*16 + 8 + t] = sv;
    }
  }

  // ---- dis_node ----
  const F3 x0 = ldatom(X,n,0), x1 = ldatom(X,n,1), x2 = ldatom(X,n,2), x3 = ldatom(X,n,3);
  {
    float buf[16];
    rbf16(buf, dist_eps(x0, x1));
    #pragma unroll
    for (int t=0;t<16;++t) out[O_DISNODE + n*48 + t] = buf[t];
    rbf16(buf, dist_eps(x2, x1));
    #pragma unroll
    for (int t=0;t<16;++t) out[O_DISNODE + n*48 + 16 + t] = buf[t];
    rbf16(buf, dist_eps(x3, x1));
    #pragma unroll
    for (int t=0;t<16;++t) out[O_DISNODE + n*48 + 32 + t] = buf[t];
  }

  // ---- angle_node ----
  {
    const bool am = !((l <= 1) || ((l == LL-1) && (b < BB-1)));
    const float amf = am ? 1.f : 0.f;
    const int t0 = 3*n - 1;
    F3 P[6];
    #pragma unroll
    for (int q = 0; q < 6; ++q){
      int t = t0 + q;
      t = t < 0 ? 0 : (t > 3*NN - 1 ? 3*NN - 1 : t);
      const int nn2 = t / 3, aa = t - nn2*3;
      P[q] = ldatom(X, nn2, aa);
    }
    F3 U[5];
    #pragma unroll
    for (int q = 0; q < 5; ++q) U[q] = normf3(subf3(P[q+1], P[q]));
    #pragma unroll
    for (int cc = 0; cc < 3; ++cc){
      const int m = 3*n + cc - 1;
      float cD = 1.f, sD = 0.f, cA = 1.f, sA = 0.f;
      if (m >= 0 && m <= 3*NN - 4){
        const F3 u2 = U[cc], u1 = U[cc+1], u0 = U[cc+2];
        const F3 n2 = normf3(crossf3(u2, u1));
        const F3 n1 = normf3(crossf3(u1, u0));
        const float cd_ = clampf(dotf3(n2, n1), -1.f + EPSF, 1.f - EPSF);
        const float sg = sgnf(dotf3(u2, n1));
        cD = cd_;
        sD = sg * sqrtf(fmaxf(1.f - cd_*cd_, 0.f));
        const float ca_ = clampf(dotf3(u2, u1), -1.f + EPSF, 1.f - EPSF);
        cA = ca_;
        sA = sqrtf(fmaxf(1.f - ca_*ca_, 0.f));
      }
      out[O_ANGNODE + n*12 + cc]     = cD * amf;
      out[O_ANGNODE + n*12 + 3 + cc] = sD * amf;
      out[O_ANGNODE + n*12 + 6 + cc] = cA * amf;
      out[O_ANGNODE + n*12 + 9 + cc] = sA * amf;
    }
  }

  // ---- direct_node ----
  {
    const F3 vs[3] = { subf3(x0, x1), subf3(x2, x1), subf3(x3, x1) };
    #pragma unroll
    for (int ai = 0; ai < 3; ++ai){
      F3 w = mkf3(dotf3(O0, vs[ai]), dotf3(O1, vs[ai]), dotf3(O2, vs[ai]));
      w = normf3(w);
      out[O_DIRNODE + n*9 + ai*3 + 0] = w.x;
      out[O_DIRNODE + n*9 + ai*3 + 1] = w.y;
      out[O_DIRNODE + n*9 + ai*3 + 2] = w.z;
    }
  }
}

// ==== kernel 3: ctx/inter + angle_edge + direct_edge + edge_pos (coalesced) ====
__global__ __launch_bounds__(256) void edge_small_kernel(const float* __restrict__ X,
                                                         const int* __restrict__ seg,
                                                         const float* __restrict__ ws,
                                                         float* __restrict__ out){
  __shared__ float s_ang[4][257];
  __shared__ float s_dir[9][257];
  __shared__ float s_pos[16][257];
  const int tid = threadIdx.x;
  const int e0 = blockIdx.x * 256;
  const int e = e0 + tid;
  const int n = e / 9;
  const int c = (int)out[O_EIDX + NE + e];

  const float ctx = (seg[n] == seg[c]) ? 1.f : 0.f;

  // edge_pos staging
  {
    const float p = (float)(n - c);
    #pragma unroll
    for (int t = 0; t < 8; ++t){
      float sv, cv;
      __sincosf(p * frq(t), &sv, &cv);
      s_pos[t][tid] = cv;
      s_pos[8 + t][tid] = sv;
    }
  }

  const float4* W = (const float4*)ws;
  const float4 r0 = W[n*3+0], r1 = W[n*3+1], r2 = W[n*3+2];
  const float4 c0 = W[c*3+0], c1 = W[c*3+1], c2 = W[c*3+2];
  const F3 Ar0 = mkf3(r0.x,r0.y,r0.z), Ar1 = mkf3(r1.x,r1.y,r1.z), Ar2 = mkf3(r2.x,r2.y,r2.z);
  const F3 Ac0 = mkf3(c0.x,c0.y,c0.z), Ac1 = mkf3(c1.x,c1.y,c1.z), Ac2 = mkf3(c2.x,c2.y,c2.z);

  // angle_edge: quaternion of R = Or^T * Oc
  {
    const float R00 = Ar0.x*Ac0.x + Ar1.x*Ac1.x + Ar2.x*Ac2.x;
    const float R01 = Ar0.x*Ac0.y + Ar1.x*Ac1.y + Ar2.x*Ac2.y;
    const float R02 = Ar0.x*Ac0.z + Ar1.x*Ac1.z + Ar2.x*Ac2.z;
    const float R10 = Ar0.y*Ac0.x + Ar1.y*Ac1.x + Ar2.y*Ac2.x;
    const float R11 = Ar0.y*Ac0.y + Ar1.y*Ac1.y + Ar2.y*Ac2.y;
    const float R12 = Ar0.y*Ac0.z + Ar1.y*Ac1.z + Ar2.y*Ac2.z;
    const float R20 = Ar0.z*Ac0.x + Ar1.z*Ac1.x + Ar2.z*Ac2.x;
    const float R21 = Ar0.z*Ac0.y + Ar1.z*Ac1.y + Ar2.z*Ac2.y;
    const float R22 = Ar0.z*Ac0.z + Ar1.z*Ac1.z + Ar2.z*Ac2.z;
    const float m0 = 0.5f * sqrtf(fabsf(1.f + R00 - R11 - R22) + 1e-12f);
    const float m1 = 0.5f * sqrtf(fabsf(1.f - R00 + R11 - R22) + 1e-12f);
    const float m2 = 0.5f * sqrtf(fabsf(1.f - R00 - R11 + R22) + 1e-12f);
    const float qx = sgnf(R21 - R12) * m0;
    const float qy = sgnf(R02 - R20) * m1;
    const float qz = sgnf(R10 - R01) * m2;
    const float qw = sqrtf(fmaxf(1.f + R00 + R11 + R22, 0.f) + 1e-12f) * 0.5f;
    const float qn = fmaxf(sqrtf(qx*qx + qy*qy + qz*qz + qw*qw), 1e-12f);
    s_ang[0][tid] = qx / qn;
    s_ang[1][tid] = qy / qn;
    s_ang[2][tid] = qz / qn;
    s_ang[3][tid] = qw / qn;
  }

  // direct_edge: atoms {0,2,3} of row node, in col frame
  {
    const F3 xc1 = ldatom(X, c, 1);
    const int atoms[3] = {0, 2, 3};
    #pragma unroll
    for (int ai = 0; ai < 3; ++ai){
      const F3 xr = ldatom(X, n, atoms[ai]);
      const F3 vv = subf3(xr, xc1);
      F3 w = mkf3(dotf3(Ac0, vv), dotf3(Ac1, vv), dotf3(Ac2, vv));
      w = normf3(w);
      s_dir[ai*3+0][tid] = w.x;
      s_dir[ai*3+1][tid] = w.y;
      s_dir[ai*3+2][tid] = w.z;
    }
  }
  __syncthreads();

  out[O_CTX + e]   = ctx;
  out[O_INTER + e] = 1.f - ctx;
  #pragma unroll
  for (int i = 0; i < 4; ++i){
    const int f = tid + 256*i;
    out[O_ANGEDGE + e0*4 + f] = s_ang[f & 3][f >> 2];
  }
  #pragma unroll
  for (int i = 0; i < 9; ++i){
    const int f = tid + 256*i;
    out[O_DIREDGE + e0*9 + f] = s_dir[f % 9][f / 9];
  }
  #pragma unroll
  for (int i = 0; i < 16; ++i){
    const int f = tid + 256*i;
    out[O_EDGEPOS + e0*16 + f] = s_pos[f & 15][f >> 4];
  }
}

// ============ kernel 4: dis_edge (float4 stores, 4 channels/thread) ============
__global__ __launch_bounds__(256) void dis_edge_kernel(const float* __restrict__ X,
                                                       float* __restrict__ out){
  const int gid = blockIdx.x * 256 + threadIdx.x;   // < NE*16
  const int e = gid >> 4, t = gid & 15;
  const int a = t >> 2, q = t & 3;                  // atom, channel-quad
  const int n = e / 9;
  const int c = (int)out[O_EIDX + NE + e];
  const F3 xr = ldatom(X, n, a);
  const F3 xc = ldatom(X, c, 1);
  const float d = dist_eps(xr, xc);
  float4 rr;
  {
    const float ch = (float)(q * 4);
    const float z0 = (d - (ch + 0.f) * (20.0f/15.0f)) * (1.0f/1.25f);
    const float z1 = (d - (ch + 1.f) * (20.0f/15.0f)) * (1.0f/1.25f);
    const float z2 = (d - (ch + 2.f) * (20.0f/15.0f)) * (1.0f/1.25f);
    const float z3 = (d - (ch + 3.f) * (20.0f/15.0f)) * (1.0f/1.25f);
    rr = make_float4(__expf(-z0*z0), __expf(-z1*z1), __expf(-z2*z2), __expf(-z3*z3));
  }
  ((float4*)(out + O_DISEDGE))[gid] = rr;
}

extern "C" void kernel_launch(void* const* d_in, const int* in_sizes, int n_in,
                              void* d_out, int out_size, void* d_ws, size_t ws_size,
                              hipStream_t stream) {
  const float* X = (const float*)d_in[0];
  const int* seg = (const int*)d_in[1];
  float* out = (float*)d_out;
  float* ws = (float*)d_ws;   // 32768*12 floats = 1.57 MB of O-frames
  topk_kernel<<<NN/ROWS, 256, 0, stream>>>(X, out);        // edge_index
  node_kernel<<<NN/256, 256, 0, stream>>>(X, ws, out);     // node features + frames
  edge_small_kernel<<<NE/256, 256, 0, stream>>>(X, seg, ws, out);
  dis_edge_kernel<<<(NE*16)/256, 256, 0, stream>>>(X, out);
}